// Round 5
// baseline (216.634 us; speedup 1.0000x reference)
//
#include <hip/hip_runtime.h>

constexpr int IMW  = 96;
constexpr int NPIX = 9216;
constexpr int TB   = 256;            // threads per block
constexpr int JT   = 4;              // j's per thread
constexpr int JB   = NPIX/(TB*JT);   // 9 j-blocks
constexpr int SI   = 192;            // staged i's per segment (2 rows)
constexpr int NSEG = NPIX/SI;        // 48 segments
constexpr int NBIL = JB*NSEG;        // 432 blocks
constexpr int NUPD = NPIX/TB;        // 36 blocks (epilogue)

constexpr float LCLIP = 18.420681f;               // -log(1e-8)
constexpr float LOG2E = 1.4426950408889634f;
constexpr float C1 = -LOG2E/18.0f;                // gaussian (sxy=3), base-2
constexpr float C2 = -LOG2E/5000.0f;              // bilateral spatial (sxy=50)
constexpr float C3 = -LOG2E/400.0f;               // bilateral feature (2*df^2/(2*20^2))

// One launch = one mean-field iteration.
// MODE 0: q_t from mask directly; also writes pksum (column sums of K).
// MODE 1: q_t reconstructed per-block from previous launch's partials.
// Partials pcur[seg][j] = sum_{i in seg} q_t[i] * Kfull[i,j]  (diag included, =13).
template<int MODE>
__global__ __launch_bounds__(TB) void k_iter(const float* __restrict__ img,
                                             const int* __restrict__ mask,
                                             const float* __restrict__ pprev,
                                             float* __restrict__ pcur,
                                             float* __restrict__ pksum,
                                             const float* __restrict__ qprev,
                                             float* __restrict__ qcur){
    __shared__ float4 st[SI];
    __shared__ float  wg[192];        // 3*exp2(C1*d^2), d = u-95
    const int tid = threadIdx.x;
    const int jb  = blockIdx.x / NSEG;
    const int seg = blockIdx.x % NSEG;
    const int i0  = seg * SI;

    if (tid < 191){
        float d = (float)(tid - 95);
        wg[tid] = 3.0f * exp2f(C1 * d * d);
    }

    // ---- phase 1: q_t for this block's staged i's ----
    if (tid < SI){
        int i = i0 + tid;
        float fi = img[i];
        float qi;
        if (MODE == 0){
            qi = (mask[i] == 0) ? (1.0f/(1.0f + __expf( LCLIP)))
                                : (1.0f/(1.0f + __expf(-LCLIP)));
        } else {
            float m = 0.f, kk = 0.f;
            #pragma unroll
            for (int s = 0; s < NSEG; ++s){
                m  += pprev[s*NPIX + i];
                kk += pksum[s*NPIX + i];
            }
            float duv = (mask[i] == 0) ? LCLIP : -LCLIP;
            float mnd = m - 13.0f * qprev[i];          // remove diagonal
            float delta = duv + (kk - 13.0f) - 2.0f*mnd;
            qi = 1.0f/(1.0f + __expf(delta));
        }
        float xf = (float)(tid % IMW);                 // rows are aligned (SI=2*IMW)
        // {f_i, C2*x^2 + C3*f^2, q_i, 10*q_i}
        st[tid] = make_float4(fi, fmaf(C2*xf, xf, C3*fi*fi), qi, 10.0f*qi);
        if (jb == 0) qcur[i] = qi;                     // designated writer (for next diag)
    }

    // ---- per-j setup ----
    float yj[JT], gx[JT], gf[JT], bb[JT];
    int   xji[JT];
    #pragma unroll
    for (int k = 0; k < JT; ++k){
        int j = jb*(TB*JT) + k*TB + tid;
        int xi = j % IMW, yi = j / IMW;
        xji[k] = xi;
        float xjf = (float)xi;
        yj[k] = (float)yi;
        float fj = img[j];
        gx[k] = -2.0f*C2*xjf;
        gf[k] = -2.0f*C3*fj;
        bb[k] = fmaf(C2*xjf, xjf, C3*fj*fj);
    }
    __syncthreads();

    // ---- phase 2: partial matvec (bilateral per-pair + gaussian via LDS table) ----
    float acc[JT] = {0,0,0,0};
    float ak2[JT] = {0,0,0,0};     // MODE0: sum e2
    float aw [JT] = {0,0,0,0};     // MODE0: sum wg (x part of gaussian)
    float gys[JT] = {0,0,0,0};     // MODE0: sum of gy over rows
    const int r0 = seg * 2;
    for (int r = 0; r < 2; ++r){
        float ry = (float)(r0 + r);
        float rc[JT], gy[JT], ag[JT];
        #pragma unroll
        for (int k = 0; k < JT; ++k){
            float dy = ry - yj[k];
            rc[k] = fmaf(C2*dy, dy, bb[k]);
            gy[k] = exp2f(C1*dy*dy);
            ag[k] = 0.f;
            if (MODE == 0) gys[k] += gy[k];
        }
        const float4* row = st + r*IMW;
        float xf = 0.f;
        #pragma unroll 4
        for (int x = 0; x < IMW; ++x){
            float4 s = row[x];                         // wave-uniform broadcast
            #pragma unroll
            for (int k = 0; k < JT; ++k){
                float a = fmaf(xf, gx[k], rc[k]);
                float p = fmaf(s.x, gf[k], a);
                float e = exp2f(p + s.y);              // bilateral kernel value
                acc[k]  = fmaf(s.w, e, acc[k]);        // += 10*q_i*e2
                float w = wg[x - xji[k] + 95];         // 3*exp2(C1*dx^2)
                ag[k]   = fmaf(w, s.z, ag[k]);         // += q_i * gauss_x
                if (MODE == 0){
                    ak2[k] += e;
                    if (r == 0) aw[k] += w;
                }
            }
            xf += 1.0f;
        }
        #pragma unroll
        for (int k = 0; k < JT; ++k)
            acc[k] = fmaf(gy[k], ag[k], acc[k]);       // fold gaussian row
    }
    #pragma unroll
    for (int k = 0; k < JT; ++k){
        int j = jb*(TB*JT) + k*TB + tid;
        pcur[seg*NPIX + j] = acc[k];
        if (MODE == 0)
            pksum[seg*NPIX + j] = fmaf(10.0f, ak2[k], gys[k]*aw[k]);
    }
}

// epilogue: final reduction + argmax
__global__ __launch_bounds__(TB) void k_final(const int* __restrict__ mask,
                                              const float* __restrict__ pmsg,
                                              const float* __restrict__ pksum,
                                              const float* __restrict__ qprev,
                                              float* __restrict__ out){
    int j = blockIdx.x*TB + threadIdx.x;
    float m = 0.f, kk = 0.f;
    #pragma unroll
    for (int s = 0; s < NSEG; ++s){
        m  += pmsg[s*NPIX + j];
        kk += pksum[s*NPIX + j];
    }
    float duv = (mask[j] == 0) ? LCLIP : -LCLIP;
    float mnd = m - 13.0f*qprev[j];
    float delta = duv + (kk - 13.0f) - 2.0f*mnd;
    out[j] = (delta > 0.f) ? 1.0f : 0.0f;              // argmax; tie -> label 0
}

extern "C" void kernel_launch(void* const* d_in, const int* in_sizes, int n_in,
                              void* d_out, int out_size, void* d_ws, size_t ws_size,
                              hipStream_t stream){
    const float* img  = (const float*)d_in[0];
    const int*   mask = (const int*)d_in[1];
    float* out = (float*)d_out;
    float* ws  = (float*)d_ws;

    float* pmsgA = ws;                              // partials, even iters
    float* pmsgB = pmsgA + (size_t)NSEG*NPIX;       // partials, odd iters
    float* pksum = pmsgB + (size_t)NSEG*NPIX;       // column sums of Kfull
    float* qA    = pksum + (size_t)NSEG*NPIX;       // q, even iters
    float* qB    = qA + NPIX;

    dim3 g(NBIL), b(TB);
    // t=0: q_0 from mask; writes pmsgA, pksum, qA
    k_iter<0><<<g, b, 0, stream>>>(img, mask, nullptr, pmsgA, pksum, nullptr, qA);
    // t=1..4: reconstruct q_t from prev partials, write new partials
    k_iter<1><<<g, b, 0, stream>>>(img, mask, pmsgA, pmsgB, pksum, qA, qB);
    k_iter<1><<<g, b, 0, stream>>>(img, mask, pmsgB, pmsgA, pksum, qB, qA);
    k_iter<1><<<g, b, 0, stream>>>(img, mask, pmsgA, pmsgB, pksum, qA, qB);
    k_iter<1><<<g, b, 0, stream>>>(img, mask, pmsgB, pmsgA, pksum, qB, qA);
    // final update (iteration 5) + argmax
    k_final<<<dim3(NUPD), b, 0, stream>>>(mask, pmsgA, pksum, qA, out);
}